// Round 1
// baseline (483.486 us; speedup 1.0000x reference)
//
#include <hip/hip_runtime.h>

#define BB 4
#define NN 16384
#define SS 4096
#define CIN 256
#define COUT 256

// ---------------------------------------------------------------------------
// Kernel 1: repack xyz2 [B][3][S] -> float4 {x,y,z,0} [B][S] for LDS staging
// ---------------------------------------------------------------------------
__global__ __launch_bounds__(256) void k_prep(const float* __restrict__ xyz2,
                                              float4* __restrict__ xyz2p) {
    int t = blockIdx.x * 256 + threadIdx.x;          // 0 .. B*S-1 (exact)
    int b = t >> 12;                                  // / S
    int s = t & (SS - 1);
    const float* base = xyz2 + b * 3 * SS;
    xyz2p[t] = make_float4(base[s], base[SS + s], base[2 * SS + s], 0.f);
}

// ---------------------------------------------------------------------------
// Kernel 2: G[b][s][o] = sum_c points2[b][c][s] * W[o][c] + bias[o]
// fp32 tiled GEMM: block = 64s x 64o tile, 256 threads, 4x4 micro-tile, K=16 chunks
// ---------------------------------------------------------------------------
__global__ __launch_bounds__(256) void k_gemm(const float* __restrict__ P,
                                              const float* __restrict__ W,
                                              const float* __restrict__ bias,
                                              float* __restrict__ G) {
    __shared__ float sP[16 * 64];       // [cc][s]  chunk of points2
    __shared__ float sW[16 * 68];       // [cc][o]  chunk of W^T, pad 68 to break write conflicts
    int o0 = blockIdx.x * 64;
    int s0 = blockIdx.y * 64;
    int b  = blockIdx.z;
    int t  = threadIdx.x;
    int i  = t & 15;    // s-subtile (4 rows each)
    int j  = t >> 4;    // o-subtile (4 cols each)

    float acc[4][4];
#pragma unroll
    for (int p = 0; p < 4; ++p)
#pragma unroll
        for (int q = 0; q < 4; ++q) acc[p][q] = 0.f;

    const float* Pb = P + (size_t)b * CIN * SS;

    for (int c0 = 0; c0 < CIN; c0 += 16) {
        __syncthreads();
        // stage points2 chunk: rows c0..c0+15, cols s0..s0+63 (coalesced in s)
        {
            int col = t & 63;
            int r0r = t >> 6;  // 0..3
#pragma unroll
            for (int r = 0; r < 4; ++r) {
                int row = r0r + r * 4;
                sP[row * 64 + col] = Pb[(size_t)(c0 + row) * SS + s0 + col];
            }
        }
        // stage W chunk transposed: sW[cc][oo] = W[o0+oo][c0+cc]
        {
            int cc = t & 15;
            int obase = t >> 4;  // 0..15
#pragma unroll
            for (int r = 0; r < 4; ++r) {
                int oo = obase + 16 * r;
                sW[cc * 68 + oo] = W[(size_t)(o0 + oo) * CIN + c0 + cc];
            }
        }
        __syncthreads();

#pragma unroll
        for (int cc = 0; cc < 16; ++cc) {
            float4 a  = *(const float4*)&sP[cc * 64 + i * 4];
            float4 bv = *(const float4*)&sW[cc * 68 + j * 4];
            float av[4] = {a.x, a.y, a.z, a.w};
            float bw[4] = {bv.x, bv.y, bv.z, bv.w};
#pragma unroll
            for (int p = 0; p < 4; ++p)
#pragma unroll
                for (int q = 0; q < 4; ++q)
                    acc[p][q] = fmaf(av[p], bw[q], acc[p][q]);
        }
    }

    float b0 = bias[o0 + j * 4 + 0];
    float b1 = bias[o0 + j * 4 + 1];
    float b2 = bias[o0 + j * 4 + 2];
    float b3 = bias[o0 + j * 4 + 3];
#pragma unroll
    for (int p = 0; p < 4; ++p) {
        float4 v = make_float4(acc[p][0] + b0, acc[p][1] + b1,
                               acc[p][2] + b2, acc[p][3] + b3);
        size_t off = ((size_t)b * SS + s0 + i * 4 + p) * COUT + o0 + j * 4;
        *(float4*)&G[off] = v;
    }
}

// ---------------------------------------------------------------------------
// Kernel 3: 3-NN. One thread per (b,n); xyz2 staged in LDS (64 KB), broadcast
// reads (wave-uniform s). Strict '<' keeps lax.top_k stable tie-break.
// ---------------------------------------------------------------------------
__global__ __launch_bounds__(256) void k_knn(const float4* __restrict__ xyz2p,
                                             const float* __restrict__ xyz1,
                                             float* __restrict__ wbuf,
                                             int* __restrict__ ibuf) {
    __shared__ float4 sm[SS];   // 64 KB
    int b = blockIdx.y;
    for (int i = threadIdx.x; i < SS; i += 256) sm[i] = xyz2p[b * SS + i];
    __syncthreads();

    int n = blockIdx.x * 256 + threadIdx.x;
    const float* xb = xyz1 + (size_t)b * 3 * NN;
    float x = xb[n], y = xb[NN + n], z = xb[2 * NN + n];

    float d0 = 3.4e38f, d1 = 3.4e38f, d2 = 3.4e38f;
    int i0 = 0, i1 = 0, i2 = 0;

#pragma unroll 8
    for (int s = 0; s < SS; ++s) {
        float4 p = sm[s];
        float dx = x - p.x, dy = y - p.y, dz = z - p.z;
        float d = fmaf(dx, dx, fmaf(dy, dy, dz * dz));
        if (d < d2) {
            if (d < d1) {
                d2 = d1; i2 = i1;
                if (d < d0) { d1 = d0; i1 = i0; d0 = d; i0 = s; }
                else        { d1 = d;  i1 = s; }
            } else { d2 = d; i2 = s; }
        }
    }

    float r0 = 1.0f / (d0 + 1e-8f);
    float r1 = 1.0f / (d1 + 1e-8f);
    float r2 = 1.0f / (d2 + 1e-8f);
    float inv = 1.0f / (r0 + r1 + r2);
    int gi = b * NN + n;
    wbuf[3 * gi + 0] = r0 * inv;
    wbuf[3 * gi + 1] = r1 * inv;
    wbuf[3 * gi + 2] = r2 * inv;
    ibuf[3 * gi + 0] = i0;
    ibuf[3 * gi + 1] = i1;
    ibuf[3 * gi + 2] = i2;
}

// ---------------------------------------------------------------------------
// Kernel 4: out[b][o][n] = sum_k w_k * G[b][idx_k][o]
// Lane = n (contiguous -> coalesced stores); loop over o in float4 steps,
// G rows stay hot in L1 across the 16-float line window.
// ---------------------------------------------------------------------------
__global__ __launch_bounds__(256) void k_interp(const float* __restrict__ G,
                                                const float* __restrict__ wbuf,
                                                const int* __restrict__ ibuf,
                                                float* __restrict__ out) {
    int b = blockIdx.y;
    int n = blockIdx.x * 256 + threadIdx.x;
    int gi = b * NN + n;
    float w0 = wbuf[3 * gi + 0];
    float w1 = wbuf[3 * gi + 1];
    float w2 = wbuf[3 * gi + 2];
    const float4* g0 = (const float4*)(G + ((size_t)b * SS + ibuf[3 * gi + 0]) * COUT);
    const float4* g1 = (const float4*)(G + ((size_t)b * SS + ibuf[3 * gi + 1]) * COUT);
    const float4* g2 = (const float4*)(G + ((size_t)b * SS + ibuf[3 * gi + 2]) * COUT);
    float* ob = out + (size_t)b * COUT * NN + n;

#pragma unroll 4
    for (int o4 = 0; o4 < COUT / 4; ++o4) {
        float4 a = g0[o4], c = g1[o4], e = g2[o4];
        float r0 = fmaf(w0, a.x, fmaf(w1, c.x, w2 * e.x));
        float r1 = fmaf(w0, a.y, fmaf(w1, c.y, w2 * e.y));
        float r2 = fmaf(w0, a.z, fmaf(w1, c.z, w2 * e.z));
        float r3 = fmaf(w0, a.w, fmaf(w1, c.w, w2 * e.w));
        ob[(size_t)(o4 * 4 + 0) * NN] = r0;
        ob[(size_t)(o4 * 4 + 1) * NN] = r1;
        ob[(size_t)(o4 * 4 + 2) * NN] = r2;
        ob[(size_t)(o4 * 4 + 3) * NN] = r3;
    }
}

// ---------------------------------------------------------------------------
extern "C" void kernel_launch(void* const* d_in, const int* in_sizes, int n_in,
                              void* d_out, int out_size, void* d_ws, size_t ws_size,
                              hipStream_t stream) {
    const float* xyz1    = (const float*)d_in[0];   // [B,3,N]
    const float* xyz2    = (const float*)d_in[1];   // [B,3,S]
    const float* points2 = (const float*)d_in[2];   // [B,CIN,S]
    const float* W       = (const float*)d_in[3];   // [COUT,CIN]
    const float* bias    = (const float*)d_in[4];   // [COUT]
    float* out = (float*)d_out;                     // [B,COUT,N]

    char* ws = (char*)d_ws;
    // workspace layout (all written before read, every launch):
    float4* xyz2p = (float4*)(ws);                  // 256 KB
    float*  wbuf  = (float*)(ws + 262144);          // 768 KB
    int*    ibuf  = (int*)(ws + 1048576);           // 768 KB
    float*  G     = (float*)(ws + 1835008);         // 16 MB: [B][S][COUT]

    k_prep<<<dim3((BB * SS) / 256), 256, 0, stream>>>(xyz2, xyz2p);
    k_gemm<<<dim3(COUT / 64, SS / 64, BB), 256, 0, stream>>>(points2, W, bias, G);
    k_knn<<<dim3(NN / 256, BB), 256, 0, stream>>>(xyz2p, xyz1, wbuf, ibuf);
    k_interp<<<dim3(NN / 256, BB), 256, 0, stream>>>(G, wbuf, ibuf, out);
}

// Round 2
// 366.469 us; speedup vs baseline: 1.3193x; 1.3193x over previous
//
#include <hip/hip_runtime.h>

#define BB 4
#define NN 16384
#define SS 4096
#define CIN 256
#define COUT 256

#define SC 8              // s-chunks for knn
#define SCS (SS / SC)     // 512 points per chunk
#define NPT 4             // query points per thread in knn
#define NBN (NN / (256 * NPT))  // 16 n-blocks per batch

// ---------------------------------------------------------------------------
// Kernel 1: repack xyz2 [B][3][S] -> float4 {x,y,z,0} [B][S] for LDS staging
// ---------------------------------------------------------------------------
__global__ __launch_bounds__(256) void k_prep(const float* __restrict__ xyz2,
                                              float4* __restrict__ xyz2p) {
    int t = blockIdx.x * 256 + threadIdx.x;          // 0 .. B*S-1 (exact)
    int b = t >> 12;                                  // / S
    int s = t & (SS - 1);
    const float* base = xyz2 + b * 3 * SS;
    xyz2p[t] = make_float4(base[s], base[SS + s], base[2 * SS + s], 0.f);
}

// ---------------------------------------------------------------------------
// Kernel 2: G[b][s][o] = sum_c points2[b][c][s] * W[o][c] + bias[o]
// fp32 tiled GEMM: block = 64s x 64o tile, 256 threads, 4x4 micro-tile
// ---------------------------------------------------------------------------
__global__ __launch_bounds__(256) void k_gemm(const float* __restrict__ P,
                                              const float* __restrict__ W,
                                              const float* __restrict__ bias,
                                              float* __restrict__ G) {
    __shared__ float sP[16 * 64];       // [cc][s]
    __shared__ float sW[16 * 68];       // [cc][o], pad 68
    int o0 = blockIdx.x * 64;
    int s0 = blockIdx.y * 64;
    int b  = blockIdx.z;
    int t  = threadIdx.x;
    int i  = t & 15;    // s-subtile
    int j  = t >> 4;    // o-subtile

    float acc[4][4];
#pragma unroll
    for (int p = 0; p < 4; ++p)
#pragma unroll
        for (int q = 0; q < 4; ++q) acc[p][q] = 0.f;

    const float* Pb = P + (size_t)b * CIN * SS;

    for (int c0 = 0; c0 < CIN; c0 += 16) {
        __syncthreads();
        {
            int col = t & 63;
            int r0r = t >> 6;
#pragma unroll
            for (int r = 0; r < 4; ++r) {
                int row = r0r + r * 4;
                sP[row * 64 + col] = Pb[(size_t)(c0 + row) * SS + s0 + col];
            }
        }
        {
            int cc = t & 15;
            int obase = t >> 4;
#pragma unroll
            for (int r = 0; r < 4; ++r) {
                int oo = obase + 16 * r;
                sW[cc * 68 + oo] = W[(size_t)(o0 + oo) * CIN + c0 + cc];
            }
        }
        __syncthreads();

#pragma unroll
        for (int cc = 0; cc < 16; ++cc) {
            float4 a  = *(const float4*)&sP[cc * 64 + i * 4];
            float4 bv = *(const float4*)&sW[cc * 68 + j * 4];
            float av[4] = {a.x, a.y, a.z, a.w};
            float bw[4] = {bv.x, bv.y, bv.z, bv.w};
#pragma unroll
            for (int p = 0; p < 4; ++p)
#pragma unroll
                for (int q = 0; q < 4; ++q)
                    acc[p][q] = fmaf(av[p], bw[q], acc[p][q]);
        }
    }

    float b0 = bias[o0 + j * 4 + 0];
    float b1 = bias[o0 + j * 4 + 1];
    float b2 = bias[o0 + j * 4 + 2];
    float b3 = bias[o0 + j * 4 + 3];
#pragma unroll
    for (int p = 0; p < 4; ++p) {
        float4 v = make_float4(acc[p][0] + b0, acc[p][1] + b1,
                               acc[p][2] + b2, acc[p][3] + b3);
        size_t off = ((size_t)b * SS + s0 + i * 4 + p) * COUT + o0 + j * 4;
        *(float4*)&G[off] = v;
    }
}

// ---------------------------------------------------------------------------
// Kernel 3: partial 3-NN over one s-chunk of 512, NPT=4 query points/thread.
// One ds_read feeds 4 independent distance chains; unroll keeps >=4 LDS
// reads in flight. Grid: (NBN, SC, B) = 512 blocks, 8 KB LDS.
// ---------------------------------------------------------------------------
__global__ __launch_bounds__(256) void k_knn(const float4* __restrict__ xyz2p,
                                             const float* __restrict__ xyz1,
                                             float* __restrict__ pd,
                                             int* __restrict__ pi) {
    __shared__ float4 sm[SCS];   // 8 KB
    int nb = blockIdx.x;
    int ch = blockIdx.y;
    int b  = blockIdx.z;
    int s_base = ch * SCS;
    for (int i = threadIdx.x; i < SCS; i += 256)
        sm[i] = xyz2p[b * SS + s_base + i];
    __syncthreads();

    const float* xb = xyz1 + (size_t)b * 3 * NN;
    int n0 = nb * (256 * NPT) + threadIdx.x;

    float x[NPT], y[NPT], z[NPT];
    float d0[NPT], d1[NPT], d2[NPT];
    int   i0[NPT], i1[NPT], i2[NPT];
#pragma unroll
    for (int k = 0; k < NPT; ++k) {
        int n = n0 + 256 * k;
        x[k] = xb[n]; y[k] = xb[NN + n]; z[k] = xb[2 * NN + n];
        d0[k] = d1[k] = d2[k] = 3.4e38f;
        i0[k] = i1[k] = i2[k] = 0;
    }

#pragma unroll 4
    for (int s = 0; s < SCS; ++s) {
        float4 p = sm[s];
        int gs = s_base + s;
#pragma unroll
        for (int k = 0; k < NPT; ++k) {
            float dx = x[k] - p.x, dy = y[k] - p.y, dz = z[k] - p.z;
            float d = fmaf(dx, dx, fmaf(dy, dy, dz * dz));
            if (d < d2[k]) {
                if (d < d1[k]) {
                    d2[k] = d1[k]; i2[k] = i1[k];
                    if (d < d0[k]) { d1[k] = d0[k]; i1[k] = i0[k]; d0[k] = d; i0[k] = gs; }
                    else           { d1[k] = d;  i1[k] = gs; }
                } else { d2[k] = d; i2[k] = gs; }
            }
        }
    }

#pragma unroll
    for (int k = 0; k < NPT; ++k) {
        int n = n0 + 256 * k;
        size_t base = ((size_t)(b * NN + n) * SC + ch) * 3;
        pd[base + 0] = d0[k]; pd[base + 1] = d1[k]; pd[base + 2] = d2[k];
        pi[base + 0] = i0[k]; pi[base + 1] = i1[k]; pi[base + 2] = i2[k];
    }
}

// ---------------------------------------------------------------------------
// Kernel 4: merge 8 partial top-3s (chunk order preserves top_k tie-break),
// compute weights, gather G rows, write out[b][o][n].
// ---------------------------------------------------------------------------
__global__ __launch_bounds__(256) void k_interp(const float* __restrict__ G,
                                                const float* __restrict__ pd,
                                                const int* __restrict__ pi,
                                                float* __restrict__ out) {
    int b = blockIdx.y;
    int n = blockIdx.x * 256 + threadIdx.x;
    size_t pbase = (size_t)(b * NN + n) * (SC * 3);

    float d0 = 3.4e38f, d1 = 3.4e38f, d2 = 3.4e38f;
    int i0 = 0, i1 = 0, i2 = 0;
#pragma unroll
    for (int c = 0; c < SC * 3; ++c) {
        float d = pd[pbase + c];
        int   s = pi[pbase + c];
        if (d < d2) {
            if (d < d1) {
                d2 = d1; i2 = i1;
                if (d < d0) { d1 = d0; i1 = i0; d0 = d; i0 = s; }
                else        { d1 = d;  i1 = s; }
            } else { d2 = d; i2 = s; }
        }
    }

    float r0 = 1.0f / (d0 + 1e-8f);
    float r1 = 1.0f / (d1 + 1e-8f);
    float r2 = 1.0f / (d2 + 1e-8f);
    float inv = 1.0f / (r0 + r1 + r2);
    float w0 = r0 * inv, w1 = r1 * inv, w2 = r2 * inv;

    const float4* g0 = (const float4*)(G + ((size_t)b * SS + i0) * COUT);
    const float4* g1 = (const float4*)(G + ((size_t)b * SS + i1) * COUT);
    const float4* g2 = (const float4*)(G + ((size_t)b * SS + i2) * COUT);
    float* ob = out + (size_t)b * COUT * NN + n;

#pragma unroll 4
    for (int o4 = 0; o4 < COUT / 4; ++o4) {
        float4 a = g0[o4], c = g1[o4], e = g2[o4];
        float r0v = fmaf(w0, a.x, fmaf(w1, c.x, w2 * e.x));
        float r1v = fmaf(w0, a.y, fmaf(w1, c.y, w2 * e.y));
        float r2v = fmaf(w0, a.z, fmaf(w1, c.z, w2 * e.z));
        float r3v = fmaf(w0, a.w, fmaf(w1, c.w, w2 * e.w));
        ob[(size_t)(o4 * 4 + 0) * NN] = r0v;
        ob[(size_t)(o4 * 4 + 1) * NN] = r1v;
        ob[(size_t)(o4 * 4 + 2) * NN] = r2v;
        ob[(size_t)(o4 * 4 + 3) * NN] = r3v;
    }
}

// ---------------------------------------------------------------------------
extern "C" void kernel_launch(void* const* d_in, const int* in_sizes, int n_in,
                              void* d_out, int out_size, void* d_ws, size_t ws_size,
                              hipStream_t stream) {
    const float* xyz1    = (const float*)d_in[0];   // [B,3,N]
    const float* xyz2    = (const float*)d_in[1];   // [B,3,S]
    const float* points2 = (const float*)d_in[2];   // [B,CIN,S]
    const float* W       = (const float*)d_in[3];   // [COUT,CIN]
    const float* bias    = (const float*)d_in[4];   // [COUT]
    float* out = (float*)d_out;                     // [B,COUT,N]

    char* ws = (char*)d_ws;
    // workspace layout (bytes):
    //   xyz2p : 0        .. 256 KB
    //   pd    : 262144   .. +6 MB   (B*N*SC*3 floats)
    //   pi    : 6553600  .. +6 MB
    //   G     : 12845056 .. +16 MB  [B][S][COUT]
    float4* xyz2p = (float4*)(ws);
    float*  pd    = (float*)(ws + 262144);
    int*    pi    = (int*)(ws + 6553600);
    float*  G     = (float*)(ws + 12845056);

    k_prep<<<dim3((BB * SS) / 256), 256, 0, stream>>>(xyz2, xyz2p);
    k_gemm<<<dim3(COUT / 64, SS / 64, BB), 256, 0, stream>>>(points2, W, bias, G);
    k_knn<<<dim3(NBN, SC, BB), 256, 0, stream>>>(xyz2p, xyz1, pd, pi);
    k_interp<<<dim3(NN / 256, BB), 256, 0, stream>>>(G, pd, pi, out);
}

// Round 3
// 273.663 us; speedup vs baseline: 1.7667x; 1.3391x over previous
//
#include <hip/hip_runtime.h>

#define BB 4
#define NN 16384
#define SS 4096
#define CIN 256
#define COUT 256

#define SC 8              // s-chunks for knn
#define SCS (SS / SC)     // 512 points per chunk
#define NPT 2             // query points per thread in knn
#define NBN (NN / (256 * NPT))  // 32 n-blocks per batch -> grid 32*8*4=1024

// ---------------------------------------------------------------------------
// Kernel 1: repack xyz2 [B][3][S] -> float4 {x,y,z,0} [B][S] for LDS staging
// ---------------------------------------------------------------------------
__global__ __launch_bounds__(256) void k_prep(const float* __restrict__ xyz2,
                                              float4* __restrict__ xyz2p) {
    int t = blockIdx.x * 256 + threadIdx.x;          // 0 .. B*S-1 (exact)
    int b = t >> 12;                                  // / S
    int s = t & (SS - 1);
    const float* base = xyz2 + b * 3 * SS;
    xyz2p[t] = make_float4(base[s], base[SS + s], base[2 * SS + s], 0.f);
}

// ---------------------------------------------------------------------------
// Kernel 2: G[b][s][o] = sum_c points2[b][c][s] * W[o][c] + bias[o]
// fp32 tiled GEMM: block = 64s x 64o tile, 256 threads, 4x4 micro-tile
// ---------------------------------------------------------------------------
__global__ __launch_bounds__(256) void k_gemm(const float* __restrict__ P,
                                              const float* __restrict__ W,
                                              const float* __restrict__ bias,
                                              float* __restrict__ G) {
    __shared__ float sP[16 * 64];       // [cc][s]
    __shared__ float sW[16 * 68];       // [cc][o], pad 68
    int o0 = blockIdx.x * 64;
    int s0 = blockIdx.y * 64;
    int b  = blockIdx.z;
    int t  = threadIdx.x;
    int i  = t & 15;    // s-subtile
    int j  = t >> 4;    // o-subtile

    float acc[4][4];
#pragma unroll
    for (int p = 0; p < 4; ++p)
#pragma unroll
        for (int q = 0; q < 4; ++q) acc[p][q] = 0.f;

    const float* Pb = P + (size_t)b * CIN * SS;

    for (int c0 = 0; c0 < CIN; c0 += 16) {
        __syncthreads();
        {
            int col = t & 63;
            int r0r = t >> 6;
#pragma unroll
            for (int r = 0; r < 4; ++r) {
                int row = r0r + r * 4;
                sP[row * 64 + col] = Pb[(size_t)(c0 + row) * SS + s0 + col];
            }
        }
        {
            int cc = t & 15;
            int obase = t >> 4;
#pragma unroll
            for (int r = 0; r < 4; ++r) {
                int oo = obase + 16 * r;
                sW[cc * 68 + oo] = W[(size_t)(o0 + oo) * CIN + c0 + cc];
            }
        }
        __syncthreads();

#pragma unroll
        for (int cc = 0; cc < 16; ++cc) {
            float4 a  = *(const float4*)&sP[cc * 64 + i * 4];
            float4 bv = *(const float4*)&sW[cc * 68 + j * 4];
            float av[4] = {a.x, a.y, a.z, a.w};
            float bw[4] = {bv.x, bv.y, bv.z, bv.w};
#pragma unroll
            for (int p = 0; p < 4; ++p)
#pragma unroll
                for (int q = 0; q < 4; ++q)
                    acc[p][q] = fmaf(av[p], bw[q], acc[p][q]);
        }
    }

    float b0 = bias[o0 + j * 4 + 0];
    float b1 = bias[o0 + j * 4 + 1];
    float b2 = bias[o0 + j * 4 + 2];
    float b3 = bias[o0 + j * 4 + 3];
#pragma unroll
    for (int p = 0; p < 4; ++p) {
        float4 v = make_float4(acc[p][0] + b0, acc[p][1] + b1,
                               acc[p][2] + b2, acc[p][3] + b3);
        size_t off = ((size_t)b * SS + s0 + i * 4 + p) * COUT + o0 + j * 4;
        *(float4*)&G[off] = v;
    }
}

// ---------------------------------------------------------------------------
// Kernel 3: partial 3-NN over one s-chunk of 512, NPT queries/thread.
// BRANCHLESS insert (cndmask, no exec-mask divergence): 19 VALU/pair.
// Grid: (NBN, SC, B) = 1024 blocks -> 4 blocks/CU, 16 waves/CU.
// ---------------------------------------------------------------------------
__global__ __launch_bounds__(256) void k_knn(const float4* __restrict__ xyz2p,
                                             const float* __restrict__ xyz1,
                                             float* __restrict__ pd,
                                             int* __restrict__ pi) {
    __shared__ float4 sm[SCS];   // 8 KB
    int nb = blockIdx.x;
    int ch = blockIdx.y;
    int b  = blockIdx.z;
    int s_base = ch * SCS;
    for (int i = threadIdx.x; i < SCS; i += 256)
        sm[i] = xyz2p[b * SS + s_base + i];
    __syncthreads();

    const float* xb = xyz1 + (size_t)b * 3 * NN;
    int n0 = nb * (256 * NPT) + threadIdx.x;

    float x[NPT], y[NPT], z[NPT];
    float d0[NPT], d1[NPT], d2[NPT];
    int   i0[NPT], i1[NPT], i2[NPT];
#pragma unroll
    for (int k = 0; k < NPT; ++k) {
        int n = n0 + 256 * k;
        x[k] = xb[n]; y[k] = xb[NN + n]; z[k] = xb[2 * NN + n];
        d0[k] = d1[k] = d2[k] = 3.4e38f;
        i0[k] = i1[k] = i2[k] = 0;
    }

#pragma unroll 8
    for (int s = 0; s < SCS; ++s) {
        float4 p = sm[s];
        int gs = s_base + s;
#pragma unroll
        for (int k = 0; k < NPT; ++k) {
            float dx = x[k] - p.x, dy = y[k] - p.y, dz = z[k] - p.z;
            float d = fmaf(dx, dx, fmaf(dy, dy, dz * dz));
            bool c2 = d < d2[k];
            bool c1 = d < d1[k];
            bool c0 = d < d0[k];
            // order: d2 reads old d1; d1 reads old d0
            d2[k] = c1 ? d1[k] : (c2 ? d : d2[k]);
            i2[k] = c1 ? i1[k] : (c2 ? gs : i2[k]);
            d1[k] = c0 ? d0[k] : (c1 ? d : d1[k]);
            i1[k] = c0 ? i0[k] : (c1 ? gs : i1[k]);
            d0[k] = c0 ? d : d0[k];
            i0[k] = c0 ? gs : i0[k];
        }
    }

#pragma unroll
    for (int k = 0; k < NPT; ++k) {
        int n = n0 + 256 * k;
        size_t base = ((size_t)(b * NN + n) * SC + ch) * 3;
        pd[base + 0] = d0[k]; pd[base + 1] = d1[k]; pd[base + 2] = d2[k];
        pi[base + 0] = i0[k]; pi[base + 1] = i1[k]; pi[base + 2] = i2[k];
    }
}

// ---------------------------------------------------------------------------
// Kernel 4: merge 8 partial top-3s (chunk order preserves top_k tie-break),
// compute weights, gather G rows, write out[b][o][n].
// ---------------------------------------------------------------------------
__global__ __launch_bounds__(256) void k_interp(const float* __restrict__ G,
                                                const float* __restrict__ pd,
                                                const int* __restrict__ pi,
                                                float* __restrict__ out) {
    int b = blockIdx.y;
    int n = blockIdx.x * 256 + threadIdx.x;
    size_t pbase = (size_t)(b * NN + n) * (SC * 3);

    float d0 = 3.4e38f, d1 = 3.4e38f, d2 = 3.4e38f;
    int i0 = 0, i1 = 0, i2 = 0;
#pragma unroll
    for (int c = 0; c < SC * 3; ++c) {
        float d = pd[pbase + c];
        int   s = pi[pbase + c];
        bool c2 = d < d2;
        bool c1 = d < d1;
        bool c0 = d < d0;
        d2 = c1 ? d1 : (c2 ? d : d2);
        i2 = c1 ? i1 : (c2 ? s : i2);
        d1 = c0 ? d0 : (c1 ? d : d1);
        i1 = c0 ? i0 : (c1 ? s : i1);
        d0 = c0 ? d : d0;
        i0 = c0 ? s : i0;
    }

    float r0 = 1.0f / (d0 + 1e-8f);
    float r1 = 1.0f / (d1 + 1e-8f);
    float r2 = 1.0f / (d2 + 1e-8f);
    float inv = 1.0f / (r0 + r1 + r2);
    float w0 = r0 * inv, w1 = r1 * inv, w2 = r2 * inv;

    const float4* g0 = (const float4*)(G + ((size_t)b * SS + i0) * COUT);
    const float4* g1 = (const float4*)(G + ((size_t)b * SS + i1) * COUT);
    const float4* g2 = (const float4*)(G + ((size_t)b * SS + i2) * COUT);
    float* ob = out + (size_t)b * COUT * NN + n;

#pragma unroll 4
    for (int o4 = 0; o4 < COUT / 4; ++o4) {
        float4 a = g0[o4], c = g1[o4], e = g2[o4];
        float r0v = fmaf(w0, a.x, fmaf(w1, c.x, w2 * e.x));
        float r1v = fmaf(w0, a.y, fmaf(w1, c.y, w2 * e.y));
        float r2v = fmaf(w0, a.z, fmaf(w1, c.z, w2 * e.z));
        float r3v = fmaf(w0, a.w, fmaf(w1, c.w, w2 * e.w));
        ob[(size_t)(o4 * 4 + 0) * NN] = r0v;
        ob[(size_t)(o4 * 4 + 1) * NN] = r1v;
        ob[(size_t)(o4 * 4 + 2) * NN] = r2v;
        ob[(size_t)(o4 * 4 + 3) * NN] = r3v;
    }
}

// ---------------------------------------------------------------------------
extern "C" void kernel_launch(void* const* d_in, const int* in_sizes, int n_in,
                              void* d_out, int out_size, void* d_ws, size_t ws_size,
                              hipStream_t stream) {
    const float* xyz1    = (const float*)d_in[0];   // [B,3,N]
    const float* xyz2    = (const float*)d_in[1];   // [B,3,S]
    const float* points2 = (const float*)d_in[2];   // [B,CIN,S]
    const float* W       = (const float*)d_in[3];   // [COUT,CIN]
    const float* bias    = (const float*)d_in[4];   // [COUT]
    float* out = (float*)d_out;                     // [B,COUT,N]

    char* ws = (char*)d_ws;
    // workspace layout (bytes):
    //   xyz2p : 0        .. 256 KB
    //   pd    : 262144   .. +6 MB   (B*N*SC*3 floats)
    //   pi    : 6553600  .. +6 MB
    //   G     : 12845056 .. +16 MB  [B][S][COUT]
    float4* xyz2p = (float4*)(ws);
    float*  pd    = (float*)(ws + 262144);
    int*    pi    = (int*)(ws + 6553600);
    float*  G     = (float*)(ws + 12845056);

    k_prep<<<dim3((BB * SS) / 256), 256, 0, stream>>>(xyz2, xyz2p);
    k_gemm<<<dim3(COUT / 64, SS / 64, BB), 256, 0, stream>>>(points2, W, bias, G);
    k_knn<<<dim3(NBN, SC, BB), 256, 0, stream>>>(xyz2p, xyz1, pd, pi);
    k_interp<<<dim3(NN / 256, BB), 256, 0, stream>>>(G, pd, pi, out);
}

// Round 4
// 266.398 us; speedup vs baseline: 1.8149x; 1.0273x over previous
//
#include <hip/hip_runtime.h>

#define BB 4
#define NN 16384
#define SS 4096
#define CIN 256
#define COUT 256

#define SC 8                 // s-chunks for knn
#define SCS (SS / SC)        // 512 points per chunk
#define KNNB (32 * SC * BB)  // nb(32) x ch(8) x b(4) = 1024 knn blocks (NPT=2)
#define GEMMB ((COUT / 64) * (SS / 64) * BB)  // 4*64*4 = 1024 gemm blocks

// ---------------------------------------------------------------------------
// Fused kernel: blocks [0, KNNB) do partial 3-NN; blocks [KNNB, KNNB+GEMMB)
// do the G = W*points2 + b GEMM. Independent work, overlapped in one launch.
// LDS aliased: knn uses 512 float4 (8 KB); gemm uses sP(4 KB)+sW(4.25 KB).
// ---------------------------------------------------------------------------
__global__ __launch_bounds__(256) void k_fused(const float* __restrict__ xyz1,
                                               const float* __restrict__ xyz2,
                                               const float* __restrict__ P,
                                               const float* __restrict__ W,
                                               const float* __restrict__ bias,
                                               float* __restrict__ G,
                                               float* __restrict__ pd,
                                               int* __restrict__ pi) {
    __shared__ float4 smv[528];   // 8448 B, aliased by both paths
    int bid = blockIdx.x;
    int t   = threadIdx.x;

    if (bid < KNNB) {
        // ---------------- knn path ----------------
        int nb = bid & 31;
        int ch = (bid >> 5) & 7;
        int b  = bid >> 8;
        int s0 = ch * SCS;

        // stage chunk: x,y,z coalesced rows; .w = |p2|^2
        const float* x2 = xyz2 + (size_t)b * 3 * SS;
        for (int i = t; i < SCS; i += 256) {
            float px = x2[s0 + i];
            float py = x2[SS + s0 + i];
            float pz = x2[2 * SS + s0 + i];
            smv[i] = make_float4(px, py, pz, fmaf(px, px, fmaf(py, py, pz * pz)));
        }
        __syncthreads();

        // two queries per thread (scalar state -- no arrays)
        int n0 = nb * 512 + t;          // query A
        int n1q = n0 + 256;             // query B
        const float* xb = xyz1 + (size_t)b * 3 * NN;
        float ax = xb[n0],  ay = xb[NN + n0],  az = xb[2 * NN + n0];
        float bx = xb[n1q], by = xb[NN + n1q], bz = xb[2 * NN + n1q];
        float an1 = fmaf(ax, ax, fmaf(ay, ay, az * az));
        float bn1 = fmaf(bx, bx, fmaf(by, by, bz * bz));
        float axm2 = -2.0f * ax, aym2 = -2.0f * ay, azm2 = -2.0f * az;
        float bxm2 = -2.0f * bx, bym2 = -2.0f * by, bzm2 = -2.0f * bz;

        float Ad0 = 3.4e38f, Ad1 = 3.4e38f, Ad2 = 3.4e38f;
        float Bd0 = 3.4e38f, Bd1 = 3.4e38f, Bd2 = 3.4e38f;
        int Ai0 = 0, Ai1 = 0, Ai2 = 0;
        int Bi0 = 0, Bi1 = 0, Bi2 = 0;

#pragma unroll 8
        for (int s = 0; s < SCS; ++s) {
            float4 p = smv[s];
            int gs = s0 + s;
            // ranking key e = -2*dot + |p2|^2  (reference's own distance form,
            // minus the per-query constant |p1|^2 which can't change ranking)
            {
                float e = fmaf(p.x, axm2, fmaf(p.y, aym2, fmaf(p.z, azm2, p.w)));
                bool c2 = e < Ad2, c1 = e < Ad1, c0 = e < Ad0;
                Ad2 = c1 ? Ad1 : (c2 ? e : Ad2);
                Ai2 = c1 ? Ai1 : (c2 ? gs : Ai2);
                Ad1 = c0 ? Ad0 : (c1 ? e : Ad1);
                Ai1 = c0 ? Ai0 : (c1 ? gs : Ai1);
                Ad0 = c0 ? e : Ad0;
                Ai0 = c0 ? gs : Ai0;
            }
            {
                float e = fmaf(p.x, bxm2, fmaf(p.y, bym2, fmaf(p.z, bzm2, p.w)));
                bool c2 = e < Bd2, c1 = e < Bd1, c0 = e < Bd0;
                Bd2 = c1 ? Bd1 : (c2 ? e : Bd2);
                Bi2 = c1 ? Bi1 : (c2 ? gs : Bi2);
                Bd1 = c0 ? Bd0 : (c1 ? e : Bd1);
                Bi1 = c0 ? Bi0 : (c1 ? gs : Bi1);
                Bd0 = c0 ? e : Bd0;
                Bi0 = c0 ? gs : Bi0;
            }
        }

        // store final d = e + |p1|^2 ; layout [ch][b][n][3] (lane-contiguous)
        {
            size_t base = ((size_t)(ch * BB + b) * NN + n0) * 3;
            pd[base + 0] = Ad0 + an1; pd[base + 1] = Ad1 + an1; pd[base + 2] = Ad2 + an1;
            pi[base + 0] = Ai0;       pi[base + 1] = Ai1;       pi[base + 2] = Ai2;
        }
        {
            size_t base = ((size_t)(ch * BB + b) * NN + n1q) * 3;
            pd[base + 0] = Bd0 + bn1; pd[base + 1] = Bd1 + bn1; pd[base + 2] = Bd2 + bn1;
            pi[base + 0] = Bi0;       pi[base + 1] = Bi1;       pi[base + 2] = Bi2;
        }
    } else {
        // ---------------- gemm path ----------------
        int g  = bid - KNNB;
        int o0 = (g & 3) * 64;
        int s0 = ((g >> 2) & 63) * 64;
        int b  = g >> 8;
        float* sP = (float*)smv;           // 16x64 floats
        float* sW = (float*)smv + 1024;    // 16x68 floats (padded)
        int i = t & 15;    // s-subtile
        int j = t >> 4;    // o-subtile

        float acc[4][4];
#pragma unroll
        for (int p = 0; p < 4; ++p)
#pragma unroll
            for (int q = 0; q < 4; ++q) acc[p][q] = 0.f;

        const float* Pb = P + (size_t)b * CIN * SS;

        for (int c0 = 0; c0 < CIN; c0 += 16) {
            __syncthreads();
            {
                int col = t & 63;
                int r0r = t >> 6;
#pragma unroll
                for (int r = 0; r < 4; ++r) {
                    int row = r0r + r * 4;
                    sP[row * 64 + col] = Pb[(size_t)(c0 + row) * SS + s0 + col];
                }
            }
            {
                int cc = t & 15;
                int obase = t >> 4;
#pragma unroll
                for (int r = 0; r < 4; ++r) {
                    int oo = obase + 16 * r;
                    sW[cc * 68 + oo] = W[(size_t)(o0 + oo) * CIN + c0 + cc];
                }
            }
            __syncthreads();

#pragma unroll
            for (int cc = 0; cc < 16; ++cc) {
                float4 a  = *(const float4*)&sP[cc * 64 + i * 4];
                float4 bv = *(const float4*)&sW[cc * 68 + j * 4];
                float av[4] = {a.x, a.y, a.z, a.w};
                float bw[4] = {bv.x, bv.y, bv.z, bv.w};
#pragma unroll
                for (int p = 0; p < 4; ++p)
#pragma unroll
                    for (int q = 0; q < 4; ++q)
                        acc[p][q] = fmaf(av[p], bw[q], acc[p][q]);
            }
        }

        float b0 = bias[o0 + j * 4 + 0];
        float b1 = bias[o0 + j * 4 + 1];
        float b2 = bias[o0 + j * 4 + 2];
        float b3 = bias[o0 + j * 4 + 3];
#pragma unroll
        for (int p = 0; p < 4; ++p) {
            float4 v = make_float4(acc[p][0] + b0, acc[p][1] + b1,
                                   acc[p][2] + b2, acc[p][3] + b3);
            size_t off = ((size_t)b * SS + s0 + i * 4 + p) * COUT + o0 + j * 4;
            *(float4*)&G[off] = v;
        }
    }
}

// ---------------------------------------------------------------------------
// interp: merge 24 partial candidates (chunk order preserves top_k tie-break),
// weights, gather G rows, write a 64-wide o-tile. Grid (NN/256, COUT/64, B)
// = 1024 blocks -> 16 waves/CU to hide gather latency.
// ---------------------------------------------------------------------------
__global__ __launch_bounds__(256) void k_interp(const float* __restrict__ G,
                                                const float* __restrict__ pd,
                                                const int* __restrict__ pi,
                                                float* __restrict__ out) {
    int b  = blockIdx.z;
    int o0 = blockIdx.y * 64;
    int n  = blockIdx.x * 256 + threadIdx.x;

    float d0 = 3.4e38f, d1 = 3.4e38f, d2 = 3.4e38f;
    int i0 = 0, i1 = 0, i2 = 0;
#pragma unroll
    for (int ch = 0; ch < SC; ++ch) {
        size_t base = ((size_t)(ch * BB + b) * NN + n) * 3;
#pragma unroll
        for (int j = 0; j < 3; ++j) {
            float d = pd[base + j];
            int   s = pi[base + j];
            bool c2 = d < d2, c1 = d < d1, c0 = d < d0;
            d2 = c1 ? d1 : (c2 ? d : d2);
            i2 = c1 ? i1 : (c2 ? s : i2);
            d1 = c0 ? d0 : (c1 ? d : d1);
            i1 = c0 ? i0 : (c1 ? s : i1);
            d0 = c0 ? d : d0;
            i0 = c0 ? s : i0;
        }
    }

    float r0 = 1.0f / (d0 + 1e-8f);
    float r1 = 1.0f / (d1 + 1e-8f);
    float r2 = 1.0f / (d2 + 1e-8f);
    float inv = 1.0f / (r0 + r1 + r2);
    float w0 = r0 * inv, w1 = r1 * inv, w2 = r2 * inv;

    const float4* g0 = (const float4*)(G + ((size_t)b * SS + i0) * COUT + o0);
    const float4* g1 = (const float4*)(G + ((size_t)b * SS + i1) * COUT + o0);
    const float4* g2 = (const float4*)(G + ((size_t)b * SS + i2) * COUT + o0);
    float* ob = out + ((size_t)b * COUT + o0) * NN + n;

#pragma unroll 4
    for (int o4 = 0; o4 < 16; ++o4) {
        float4 a = g0[o4], c = g1[o4], e = g2[o4];
        float r0v = fmaf(w0, a.x, fmaf(w1, c.x, w2 * e.x));
        float r1v = fmaf(w0, a.y, fmaf(w1, c.y, w2 * e.y));
        float r2v = fmaf(w0, a.z, fmaf(w1, c.z, w2 * e.z));
        float r3v = fmaf(w0, a.w, fmaf(w1, c.w, w2 * e.w));
        ob[(size_t)(o4 * 4 + 0) * NN] = r0v;
        ob[(size_t)(o4 * 4 + 1) * NN] = r1v;
        ob[(size_t)(o4 * 4 + 2) * NN] = r2v;
        ob[(size_t)(o4 * 4 + 3) * NN] = r3v;
    }
}

// ---------------------------------------------------------------------------
extern "C" void kernel_launch(void* const* d_in, const int* in_sizes, int n_in,
                              void* d_out, int out_size, void* d_ws, size_t ws_size,
                              hipStream_t stream) {
    const float* xyz1    = (const float*)d_in[0];   // [B,3,N]
    const float* xyz2    = (const float*)d_in[1];   // [B,3,S]
    const float* points2 = (const float*)d_in[2];   // [B,CIN,S]
    const float* W       = (const float*)d_in[3];   // [COUT,CIN]
    const float* bias    = (const float*)d_in[4];   // [COUT]
    float* out = (float*)d_out;                     // [B,COUT,N]

    char* ws = (char*)d_ws;
    // workspace layout (bytes), total ~29.4 MB (same proven footprint):
    //   pd : 0        .. 6,291,456   ([SC][B][N][3] floats)
    //   pi : 6291456  .. 12,582,912
    //   G  : 12582912 .. 29,360,128  ([B][S][COUT] floats)
    float* pd = (float*)(ws);
    int*   pi = (int*)(ws + 6291456);
    float* G  = (float*)(ws + 12582912);

    k_fused<<<dim3(KNNB + GEMMB), 256, 0, stream>>>(xyz1, xyz2, points2, W, bias,
                                                    G, pd, pi);
    k_interp<<<dim3(NN / 256, COUT / 64, BB), 256, 0, stream>>>(G, pd, pi, out);
}